// Round 5
// baseline (68.806 us; speedup 1.0000x reference)
//
#include <hip/hip_runtime.h>

#define RNN 2048
#define AH  512
#define BB  128
#define LL  196

// fast tanh: 1 - 2/(exp(2x)+1). v_exp + v_rcp, correct limits at +/-inf.
__device__ __forceinline__ float tanh_fast(float x) {
    float e = __expf(2.0f * x);
    return 1.0f - 2.0f * __builtin_amdgcn_rcpf(e + 1.0f);
}

// ---------------- k1: att_h[b][a] = sum_k h[b][k]*w[a][k] + bias[a] ----------------
// grid (16 a-groups of 32, 16 b-groups of 8), 512 thr = 8 waves; wave owns 4 a-cols
// for 8 b-rows (acc v[32]). W L2 traffic halved vs 4-b tiling (64 MB total).
// Fold-exchange reduce: 32 sums over 64 lanes in 31+1 shuffles; coalesced-ish store.
__global__ __launch_bounds__(512) void k1_atth(const float* __restrict__ h,
                                               const float* __restrict__ w,
                                               const float* __restrict__ bias,
                                               float* __restrict__ att_h) {
    __shared__ float hs[8 * RNN];                 // 64 KB: 8 h rows
    const int tid  = threadIdx.x;
    const int wv   = tid >> 6, lane = tid & 63;
    const int b0   = blockIdx.y * 8;
    const int a0   = blockIdx.x * 32 + wv * 4;

    const float4* hg  = reinterpret_cast<const float4*>(h + (size_t)b0 * RNN);
    float4*       hs4 = reinterpret_cast<float4*>(hs);
    #pragma unroll
    for (int i = 0; i < 8; ++i) hs4[tid + i * 512] = hg[tid + i * 512];
    __syncthreads();

    float v[32];
    #pragma unroll
    for (int j = 0; j < 32; ++j) v[j] = 0.f;

    const float4* w4 = reinterpret_cast<const float4*>(w);
    #pragma unroll 1
    for (int i = 0; i < 8; ++i) {                 // k-chunks of 256 floats
        const int k4 = i * 64 + lane;
        float4 hv[8];
        #pragma unroll
        for (int bl = 0; bl < 8; ++bl) hv[bl] = hs4[bl * 512 + k4];
        #pragma unroll
        for (int ai = 0; ai < 4; ++ai) {
            float4 wvv = w4[(size_t)(a0 + ai) * 512 + k4];  // 64 lanes x 16B contiguous
            #pragma unroll
            for (int bl = 0; bl < 8; ++bl)
                v[ai * 8 + bl] += wvv.x * hv[bl].x + wvv.y * hv[bl].y
                                + wvv.z * hv[bl].z + wvv.w * hv[bl].w;
        }
    }

    // fold-exchange: index bit (4..0) <- lane bit (5..1); lanes 2j,2j+1 end with sum j
    int n = 32;
    #pragma unroll
    for (int d = 32; d >= 2; d >>= 1) {
        const bool up = (lane & d) != 0;
        #pragma unroll
        for (int i = 0; i < 16; ++i) {
            if (i < n / 2) {
                float send = up ? v[i] : v[i + n / 2];
                float recv = __shfl_xor(send, d);
                v[i] = (up ? v[i + n / 2] : v[i]) + recv;
            }
        }
        n >>= 1;
    }
    v[0] += __shfl_xor(v[0], 1);

    const int j  = lane >> 1;
    const int ai = j >> 3, bl = j & 7;
    if ((lane & 1) == 0)
        att_h[(size_t)(b0 + bl) * AH + a0 + ai] = v[0] + bias[a0 + ai];
}

// ---------------- k2: scores[b][l] = sum_a tanh(iaf+att_h)*alpha_w + alpha_b -------
// one wave per (b,l); 8 waves per block.
__global__ __launch_bounds__(512) void k2_scores(const float* __restrict__ iaf,
                                                 const float* __restrict__ att_h,
                                                 const float* __restrict__ aw,
                                                 const float* __restrict__ ab,
                                                 float* __restrict__ scores) {
    const int wid  = blockIdx.x * 8 + (threadIdx.x >> 6);
    const int lane = threadIdx.x & 63;
    if (wid >= BB * LL) return;
    const int b = wid / LL, l = wid - b * LL;

    const float4* ir = reinterpret_cast<const float4*>(iaf + (size_t)(b * LL + l) * AH);
    const float4* hr = reinterpret_cast<const float4*>(att_h + (size_t)b * AH);
    const float4* ar = reinterpret_cast<const float4*>(aw);

    float s = 0.f;
    #pragma unroll
    for (int c = 0; c < 2; ++c) {
        int idx = lane + c * 64;
        float4 iv = ir[idx];
        float4 hv = hr[idx];
        float4 av = ar[idx];
        s += tanh_fast(iv.x + hv.x) * av.x
           + tanh_fast(iv.y + hv.y) * av.y
           + tanh_fast(iv.z + hv.z) * av.z
           + tanh_fast(iv.w + hv.w) * av.w;
    }
    #pragma unroll
    for (int off = 32; off; off >>= 1) s += __shfl_xor(s, off);
    if (lane == 0) scores[b * LL + l] = s + ab[0];
}

// ---------------- k4: fused softmax + out[b][d] = sum_l softmax(scores)[l]*af ------
// grid (4 d-chunks of 512, 128 b), 512 threads = 4 l-groups x 128 threads.
__global__ __launch_bounds__(512) void k4_out(const float* __restrict__ af,
                                              const float* __restrict__ scores,
                                              float* __restrict__ out) {
    const int b  = blockIdx.y;
    const int t  = threadIdx.x;
    const int lg = t >> 7;            // l-group 0..3
    const int tt = t & 127;           // thread within group
    const int d0 = blockIdx.x * 512 + tt * 4;

    __shared__ float  wsm[LL];
    __shared__ float  red[8];
    __shared__ float4 p4[4][128];

    float v0 = (t < LL) ? scores[b * LL + t] : -1e30f;
    float m = v0;
    #pragma unroll
    for (int off = 32; off; off >>= 1) m = fmaxf(m, __shfl_xor(m, off));
    if ((t & 63) == 0) red[t >> 6] = m;
    __syncthreads();
    m = fmaxf(fmaxf(fmaxf(red[0], red[1]), fmaxf(red[2], red[3])),
              fmaxf(fmaxf(red[4], red[5]), fmaxf(red[6], red[7])));
    __syncthreads();

    float e0 = (t < LL) ? __expf(v0 - m) : 0.f;
    float s = e0;
    #pragma unroll
    for (int off = 32; off; off >>= 1) s += __shfl_xor(s, off);
    if ((t & 63) == 0) red[t >> 6] = s;
    __syncthreads();
    s = red[0] + red[1] + red[2] + red[3] + red[4] + red[5] + red[6] + red[7];
    const float inv = 1.f / s;
    if (t < LL) wsm[t] = e0 * inv;
    __syncthreads();

    const float* base = af + (size_t)b * LL * RNN + d0 + (size_t)(lg * 49) * RNN;
    float4 acc = {0.f, 0.f, 0.f, 0.f};
    #pragma unroll 7
    for (int i = 0; i < 49; ++i) {
        float wl = wsm[lg * 49 + i];
        float4 v = *reinterpret_cast<const float4*>(base + (size_t)i * RNN);
        acc.x += wl * v.x; acc.y += wl * v.y; acc.z += wl * v.z; acc.w += wl * v.w;
    }
    p4[lg][tt] = acc;
    __syncthreads();

    if (lg == 0) {
        float4 a0 = p4[0][tt], a1 = p4[1][tt], a2 = p4[2][tt], a3 = p4[3][tt];
        float4 r;
        r.x = (a0.x + a1.x) + (a2.x + a3.x);
        r.y = (a0.y + a1.y) + (a2.y + a3.y);
        r.z = (a0.z + a1.z) + (a2.z + a3.z);
        r.w = (a0.w + a1.w) + (a2.w + a3.w);
        *reinterpret_cast<float4*>(out + (size_t)b * RNN + d0) = r;
    }
}

extern "C" void kernel_launch(void* const* d_in, const int* in_sizes, int n_in,
                              void* d_out, int out_size, void* d_ws, size_t ws_size,
                              hipStream_t stream) {
    const float* h    = (const float*)d_in[0];   // [128,2048]
    const float* af   = (const float*)d_in[1];   // [128,196,2048]
    const float* iaf  = (const float*)d_in[2];   // [128,196,512]
    const float* w    = (const float*)d_in[3];   // [512,2048]
    const float* bias = (const float*)d_in[4];   // [512]
    const float* aw   = (const float*)d_in[5];   // [1,512]
    const float* ab   = (const float*)d_in[6];   // [1]
    float* out = (float*)d_out;

    float* ws_f    = (float*)d_ws;
    float* att_h   = ws_f;                       // 128*512
    float* scores  = ws_f + BB * AH;             // 128*196

    k1_atth<<<dim3(16, 16), 512, 0, stream>>>(h, w, bias, att_h);

    int nwl = BB * LL;                           // 25088 waves
    k2_scores<<<(nwl + 7) / 8, 512, 0, stream>>>(iaf, att_h, aw, ab, scores);

    k4_out<<<dim3(4, BB), 512, 0, stream>>>(af, scores, out);
}

// Round 6
// 59.079 us; speedup vs baseline: 1.1647x; 1.1647x over previous
//
#include <hip/hip_runtime.h>

#define RNN 2048
#define AH  512
#define BB  128
#define LL  196

// fast tanh: 1 - 2/(exp(2x)+1). v_exp + v_rcp, correct limits at +/-inf.
__device__ __forceinline__ float tanh_fast(float x) {
    float e = __expf(2.0f * x);
    return 1.0f - 2.0f * __builtin_amdgcn_rcpf(e + 1.0f);
}

// ---------------- k1: att_h[b][a] = sum_k h[b][k]*w[a][k] + bias[a] ----------------
// (round-2 config, measured within the 61.3us total)
// Block: 256 threads = 4 waves; 4 b-rows x 32 a-cols; lanes along K; butterfly reduce.
__global__ __launch_bounds__(256) void k1_atth(const float* __restrict__ h,
                                               const float* __restrict__ w,
                                               const float* __restrict__ bias,
                                               float* __restrict__ att_h) {
    __shared__ float hs[4 * RNN];                 // 32 KB: 4 h rows
    const int tid  = threadIdx.x;
    const int wv   = tid >> 6, lane = tid & 63;
    const int b0   = blockIdx.y * 4;
    const int a0   = blockIdx.x * 32 + wv * 8;

    const float4* hg  = reinterpret_cast<const float4*>(h + (size_t)b0 * RNN);
    float4*       hs4 = reinterpret_cast<float4*>(hs);
    #pragma unroll
    for (int i = 0; i < 8; ++i) hs4[tid + i * 256] = hg[tid + i * 256];
    __syncthreads();

    float acc[8][4];
    #pragma unroll
    for (int ai = 0; ai < 8; ++ai)
        #pragma unroll
        for (int bl = 0; bl < 4; ++bl) acc[ai][bl] = 0.f;

    const float4* w4 = reinterpret_cast<const float4*>(w);
    #pragma unroll 1
    for (int i = 0; i < 8; ++i) {                 // k-chunks of 256 floats
        const int k4 = i * 64 + lane;
        float4 hv[4];
        #pragma unroll
        for (int bl = 0; bl < 4; ++bl) hv[bl] = hs4[bl * 512 + k4];
        #pragma unroll
        for (int ai = 0; ai < 8; ++ai) {
            float4 wvv = w4[(size_t)(a0 + ai) * 512 + k4];
            #pragma unroll
            for (int bl = 0; bl < 4; ++bl)
                acc[ai][bl] += wvv.x * hv[bl].x + wvv.y * hv[bl].y
                             + wvv.z * hv[bl].z + wvv.w * hv[bl].w;
        }
    }

    #pragma unroll
    for (int off = 32; off; off >>= 1)
        #pragma unroll
        for (int ai = 0; ai < 8; ++ai)
            #pragma unroll
            for (int bl = 0; bl < 4; ++bl)
                acc[ai][bl] += __shfl_xor(acc[ai][bl], off);

    if (lane == 0) {
        #pragma unroll
        for (int ai = 0; ai < 8; ++ai) {
            const float ba = bias[a0 + ai];
            #pragma unroll
            for (int bl = 0; bl < 4; ++bl)
                att_h[(b0 + bl) * AH + a0 + ai] = acc[ai][bl] + ba;
        }
    }
}

// ---------------- k2: scores[b][l] = sum_a tanh(iaf+att_h)*alpha_w + alpha_b -------
// one wave per (b,l); 8 waves per block.
__global__ __launch_bounds__(512) void k2_scores(const float* __restrict__ iaf,
                                                 const float* __restrict__ att_h,
                                                 const float* __restrict__ aw,
                                                 const float* __restrict__ ab,
                                                 float* __restrict__ scores) {
    const int wid  = blockIdx.x * 8 + (threadIdx.x >> 6);
    const int lane = threadIdx.x & 63;
    if (wid >= BB * LL) return;
    const int b = wid / LL, l = wid - b * LL;

    const float4* ir = reinterpret_cast<const float4*>(iaf + (size_t)(b * LL + l) * AH);
    const float4* hr = reinterpret_cast<const float4*>(att_h + (size_t)b * AH);
    const float4* ar = reinterpret_cast<const float4*>(aw);

    float s = 0.f;
    #pragma unroll
    for (int c = 0; c < 2; ++c) {
        int idx = lane + c * 64;
        float4 iv = ir[idx];
        float4 hv = hr[idx];
        float4 av = ar[idx];
        s += tanh_fast(iv.x + hv.x) * av.x
           + tanh_fast(iv.y + hv.y) * av.y
           + tanh_fast(iv.z + hv.z) * av.z
           + tanh_fast(iv.w + hv.w) * av.w;
    }
    #pragma unroll
    for (int off = 32; off; off >>= 1) s += __shfl_xor(s, off);
    if (lane == 0) scores[b * LL + l] = s + ab[0];
}

// ---------------- k4: fused softmax + out[b][d] = sum_l softmax(scores)[l]*af ------
// grid (4 d-chunks of 512, 128 b), 512 threads = 4 l-groups x 128 threads.
__global__ __launch_bounds__(512) void k4_out(const float* __restrict__ af,
                                              const float* __restrict__ scores,
                                              float* __restrict__ out) {
    const int b  = blockIdx.y;
    const int t  = threadIdx.x;
    const int lg = t >> 7;            // l-group 0..3
    const int tt = t & 127;           // thread within group
    const int d0 = blockIdx.x * 512 + tt * 4;

    __shared__ float  wsm[LL];
    __shared__ float  red[8];
    __shared__ float4 p4[4][128];

    float v0 = (t < LL) ? scores[b * LL + t] : -1e30f;
    float m = v0;
    #pragma unroll
    for (int off = 32; off; off >>= 1) m = fmaxf(m, __shfl_xor(m, off));
    if ((t & 63) == 0) red[t >> 6] = m;
    __syncthreads();
    m = fmaxf(fmaxf(fmaxf(red[0], red[1]), fmaxf(red[2], red[3])),
              fmaxf(fmaxf(red[4], red[5]), fmaxf(red[6], red[7])));
    __syncthreads();

    float e0 = (t < LL) ? __expf(v0 - m) : 0.f;
    float s = e0;
    #pragma unroll
    for (int off = 32; off; off >>= 1) s += __shfl_xor(s, off);
    if ((t & 63) == 0) red[t >> 6] = s;
    __syncthreads();
    s = red[0] + red[1] + red[2] + red[3] + red[4] + red[5] + red[6] + red[7];
    const float inv = 1.f / s;
    if (t < LL) wsm[t] = e0 * inv;
    __syncthreads();

    const float* base = af + (size_t)b * LL * RNN + d0 + (size_t)(lg * 49) * RNN;
    float4 acc = {0.f, 0.f, 0.f, 0.f};
    #pragma unroll 7
    for (int i = 0; i < 49; ++i) {
        float wl = wsm[lg * 49 + i];
        float4 v = *reinterpret_cast<const float4*>(base + (size_t)i * RNN);
        acc.x += wl * v.x; acc.y += wl * v.y; acc.z += wl * v.z; acc.w += wl * v.w;
    }
    p4[lg][tt] = acc;
    __syncthreads();

    if (lg == 0) {
        float4 a0 = p4[0][tt], a1 = p4[1][tt], a2 = p4[2][tt], a3 = p4[3][tt];
        float4 r;
        r.x = (a0.x + a1.x) + (a2.x + a3.x);
        r.y = (a0.y + a1.y) + (a2.y + a3.y);
        r.z = (a0.z + a1.z) + (a2.z + a3.z);
        r.w = (a0.w + a1.w) + (a2.w + a3.w);
        *reinterpret_cast<float4*>(out + (size_t)b * RNN + d0) = r;
    }
}

extern "C" void kernel_launch(void* const* d_in, const int* in_sizes, int n_in,
                              void* d_out, int out_size, void* d_ws, size_t ws_size,
                              hipStream_t stream) {
    const float* h    = (const float*)d_in[0];   // [128,2048]
    const float* af   = (const float*)d_in[1];   // [128,196,2048]
    const float* iaf  = (const float*)d_in[2];   // [128,196,512]
    const float* w    = (const float*)d_in[3];   // [512,2048]
    const float* bias = (const float*)d_in[4];   // [512]
    const float* aw   = (const float*)d_in[5];   // [1,512]
    const float* ab   = (const float*)d_in[6];   // [1]
    float* out = (float*)d_out;

    float* ws_f    = (float*)d_ws;
    float* att_h   = ws_f;                       // 128*512
    float* scores  = ws_f + BB * AH;             // 128*196

    k1_atth<<<dim3(16, 32), 256, 0, stream>>>(h, w, bias, att_h);

    int nwl = BB * LL;                           // 25088 waves
    k2_scores<<<(nwl + 7) / 8, 512, 0, stream>>>(iaf, att_h, aw, ab, scores);

    k4_out<<<dim3(4, BB), 512, 0, stream>>>(af, scores, out);
}